// Round 5
// baseline (212.329 us; speedup 1.0000x reference)
//
#include <hip/hip_runtime.h>
#include <cstdint>

#define DIM 768
#define NH 12
#define HD 64
#define SEQ 1024
#define NBH 96

// ws layout (u16 elements)
#define QOFF  ((size_t)0)
#define KOFF  ((size_t)6291456)
#define VOFF  ((size_t)12582912)
#define AOFF  ((size_t)18874368)   // attn output bf16 [8192][768]
#define XOFF  ((size_t)25165824)   // x bf16
#define WQOFF ((size_t)31457280)   // w_qkv^T bf16 [2304][768]
#define WPOFF ((size_t)33226752)   // w_proj^T bf16 [768][768]

#define QSCALE 0.18033688f  /* 0.125 * log2(e) */

// s_waitcnt immediates: vmcnt[3:0]@[3:0], expcnt@[6:4], lgkmcnt@[11:8], vmcnt[5:4]@[15:14]
#define WAIT_VM0   __builtin_amdgcn_s_waitcnt(0x0F70)            /* vmcnt(0) only */
#define WAIT_VM(n) __builtin_amdgcn_s_waitcnt(0x0F70 | (n))      /* vmcnt(n), n<16 */
#define BAR        __builtin_amdgcn_s_barrier()
#define CFENCE     __asm__ __volatile__("" ::: "memory")

typedef __attribute__((ext_vector_type(8))) __bf16 bf16x8;
typedef __attribute__((ext_vector_type(2))) __bf16 bf16x2;
typedef __attribute__((ext_vector_type(4))) float f32x4;
typedef __attribute__((ext_vector_type(4))) short s16x4;
typedef unsigned short u16;

__device__ __forceinline__ u16 f2bf(float f) {
    union { float f; unsigned u; } x; x.f = f;
    unsigned r = x.u + 0x7fffu + ((x.u >> 16) & 1u);
    return (u16)(r >> 16);
}

__device__ __forceinline__ unsigned pkbf(float a, float b) {
#if __has_builtin(__builtin_amdgcn_cvt_pk_bf16_f32)
    bf16x2 v = __builtin_amdgcn_cvt_pk_bf16_f32(a, b);
    union { bf16x2 v; unsigned u; } c; c.v = v; return c.u;
#else
    return (unsigned)f2bf(a) | ((unsigned)f2bf(b) << 16);
#endif
}

__device__ __forceinline__ void async_cp16(const void* g, void* l) {
    __builtin_amdgcn_global_load_lds((const __attribute__((address_space(1))) void*)g,
                                     (__attribute__((address_space(3))) void*)l, 16, 0, 0);
}

// ---- fused prep: x fp32->bf16 (2 float4/thread), plus both weight transposes
__global__ __launch_bounds__(256) void prep(const float* __restrict__ x,
                                            const float* __restrict__ wq,
                                            const float* __restrict__ wp,
                                            u16* __restrict__ ws) {
    const int bid = blockIdx.x;
    const int tid = threadIdx.x;
    if (bid < 3072) {
        size_t i = (size_t)bid * 512 + tid;
#pragma unroll
        for (int j = 0; j < 2; ++j, i += 256) {
            float4 v = *(const float4*)&x[i * 4];
            ushort4 o;
            o.x = f2bf(v.x); o.y = f2bf(v.y); o.z = f2bf(v.z); o.w = f2bf(v.w);
            *(ushort4*)&ws[XOFF + i * 4] = o;
        }
        return;
    }
    __shared__ float T[64][65];
    const float* w; u16* wt; int N, bx, by;
    if (bid < 3504) { int b = bid - 3072; w = wq; wt = ws + WQOFF; N = 2304; bx = b % 36; by = b / 36; }
    else            { int b = bid - 3504; w = wp; wt = ws + WPOFF; N = 768;  bx = b % 12; by = b / 12; }
    const int K = 768;
    const int k0 = by * 64, n0 = bx * 64;
    const int r = tid >> 4, c4 = (tid & 15) * 4;
#pragma unroll
    for (int i = 0; i < 4; ++i) {
        float4 v = *(const float4*)&w[(size_t)(k0 + r + 16 * i) * N + n0 + c4];
        T[r + 16 * i][c4 + 0] = v.x; T[r + 16 * i][c4 + 1] = v.y;
        T[r + 16 * i][c4 + 2] = v.z; T[r + 16 * i][c4 + 3] = v.w;
    }
    __syncthreads();
#pragma unroll
    for (int i = 0; i < 4; ++i) {
        int rr = r + 16 * i;
        ushort4 o;
        o.x = f2bf(T[c4 + 0][rr]); o.y = f2bf(T[c4 + 1][rr]);
        o.z = f2bf(T[c4 + 2][rr]); o.w = f2bf(T[c4 + 3][rr]);
        *(ushort4*)&wt[(size_t)(n0 + rr) * K + k0 + c4] = o;
    }
}

// ---- GEMM 512-thread depth-3 counted-vmcnt pipeline.
// R5 change: XCD swizzle REMOVED (block->(m,n) mapping now identical to R0's QKV).
// Theory: the swizzle relocated Q/K/V writes in per-XCD L2s away from where the
// downstream flash kernel's default-dispatched blocks re-read them (~21 us penalty
// on the total across R2/R3/R4, each sharing only this kernel).
// 8 waves 2m x 4n, tile 128x128, BK=64, 4 LDS buffers, prefetch depth 3, vmcnt(8) waits.
template <int EPI>
__global__ __launch_bounds__(512, 2) void gemm512(const u16* __restrict__ A,
                                                  const u16* __restrict__ Bt,
                                                  const float* __restrict__ bias,
                                                  float* __restrict__ outf,
                                                  u16* __restrict__ outq) {
    constexpr int NT = 12;   // K = 768 = 12 * 64
    __shared__ __align__(16) u16 As[4][128 * 64];
    __shared__ __align__(16) u16 Bs[4][128 * 64];
    const int tid = threadIdx.x;
    const int lane = tid & 63;
    const int w = tid >> 6;            // 0..7
    const int wm = w >> 2, wn = w & 3; // 2 x 4 wave grid

    const int m0 = blockIdx.y * 128, n0 = blockIdx.x * 128;   // no swizzle (R0 mapping)

    const int lgrp = lane >> 3;             // row-within-8
    const int gg = (lane & 7) ^ lgrp;       // swizzled global k-group for staging
    const u16* ga = A  + (size_t)(m0 + w * 16 + lgrp) * 768 + gg * 8;
    const u16* gb = Bt + (size_t)(n0 + w * 16 + lgrp) * 768 + gg * 8;

    const int l15 = lane & 15, qg = lane >> 4, q4 = qg * 4;

    int aoff[4][2], boff[2][2];
#pragma unroll
    for (int r = 0; r < 4; ++r) {
        int row = 64 * wm + 16 * r + l15;
#pragma unroll
        for (int kc = 0; kc < 2; ++kc)
            aoff[r][kc] = row * 64 + (((4 * kc + qg) ^ (row & 7)) << 3);
    }
#pragma unroll
    for (int c = 0; c < 2; ++c) {
        int row = 32 * wn + 16 * c + l15;
#pragma unroll
        for (int kc = 0; kc < 2; ++kc)
            boff[c][kc] = row * 64 + (((4 * kc + qg) ^ (row & 7)) << 3);
    }

    f32x4 acc[4][2] = {};

    auto stageT = [&](int t) {
        const int buf = t & 3;
        const size_t ko = (size_t)t * 64;
#pragma unroll
        for (int i = 0; i < 2; ++i) {
            async_cp16(ga + (size_t)i * 8 * 768 + ko, &As[buf][(w * 16 + i * 8) * 64]);
            async_cp16(gb + (size_t)i * 8 * 768 + ko, &Bs[buf][(w * 16 + i * 8) * 64]);
        }
    };
    auto compute = [&](int buf) {
#pragma unroll
        for (int kc = 0; kc < 2; ++kc) {
            bf16x8 af[4], bfr[2];
#pragma unroll
            for (int r = 0; r < 4; ++r) af[r] = *(const bf16x8*)&As[buf][aoff[r][kc]];
#pragma unroll
            for (int c = 0; c < 2; ++c) bfr[c] = *(const bf16x8*)&Bs[buf][boff[c][kc]];
            __builtin_amdgcn_s_setprio(1);
#pragma unroll
            for (int r = 0; r < 4; ++r)
#pragma unroll
                for (int c = 0; c < 2; ++c)
                    acc[r][c] = __builtin_amdgcn_mfma_f32_16x16x32_bf16(af[r], bfr[c], acc[r][c], 0, 0, 0);
            __builtin_amdgcn_s_setprio(0);
        }
    };

    stageT(0); stageT(1); stageT(2);

    int t = 0;
    for (; t < NT - 3; ++t) {
        WAIT_VM(8);
        BAR;
        CFENCE;
        stageT(t + 3);
        compute(t & 3);
    }
    WAIT_VM(8); BAR; CFENCE; compute(t & 3); ++t;
    WAIT_VM(4); BAR; CFENCE; compute(t & 3); ++t;
    WAIT_VM0;   BAR; CFENCE; compute(t & 3);

#pragma unroll
    for (int r = 0; r < 4; ++r) {
#pragma unroll
        for (int c = 0; c < 2; ++c) {
            const int cg = n0 + 32 * wn + 16 * c + l15;
            const float bv = bias[cg];
            const int mb = m0 + 64 * wm + 16 * r + q4;
            if constexpr (EPI == 0) {
#pragma unroll
                for (int g = 0; g < 4; ++g)
                    outf[(size_t)(mb + g) * DIM + cg] = acc[r][c][g] + bv;
            } else {
                const int which = (cg >= 1536) ? 2 : (cg >= 768 ? 1 : 0);  // uniform per block
                const int rem = cg - which * 768;
                const int h = rem >> 6, d = rem & 63;
                const int b = mb >> 10, q = mb & 1023;
                if (which == 0) {
#pragma unroll
                    for (int g = 0; g < 4; ++g)
                        outq[QOFF + ((size_t)(b * NH + h) * SEQ + q + g) * HD + d] =
                            f2bf((acc[r][c][g] + bv) * QSCALE);
                } else if (which == 1) {
#pragma unroll
                    for (int g = 0; g < 4; ++g)
                        outq[KOFF + ((size_t)(b * NH + h) * SEQ + q + g) * HD + d] =
                            f2bf(acc[r][c][g] + bv);
                } else {
                    ushort4 pk;
                    pk.x = f2bf(acc[r][c][0] + bv); pk.y = f2bf(acc[r][c][1] + bv);
                    pk.z = f2bf(acc[r][c][2] + bv); pk.w = f2bf(acc[r][c][3] + bv);
                    *(ushort4*)&outq[VOFF + ((size_t)(b * NH + h) * HD + d) * SEQ + q] = pk;
                }
            }
        }
    }
}

// ---- GEMM 256-thread R0 structure (proj): 3 blocks/CU, balanced grid.
// Tile = 128m x (32*NC)n, BK=64, single-buffer, 2 barriers/K-step.
template <int EPI, int NC>
__global__ __launch_bounds__(256, 3) void gemm256(const u16* __restrict__ A,
                                                  const u16* __restrict__ Bt,
                                                  const float* __restrict__ bias,
                                                  float* __restrict__ outf,
                                                  u16* __restrict__ outq) {
    __shared__ __align__(16) u16 As[128 * 64];
    __shared__ __align__(16) u16 Bs[32 * NC * 64];
    const int tid = threadIdx.x;
    const int lane = tid & 63;
    const int w = tid >> 6;
    const int wm = w >> 1, wn = w & 1;
    const int m0 = blockIdx.y * 128, n0 = blockIdx.x * (32 * NC);

    const int lgrp = lane >> 3;
    const int gg = (lane & 7) ^ lgrp;
    const u16* ga = A  + (size_t)(m0 + w * 32 + lgrp) * 768 + gg * 8;
    const u16* gb = Bt + (size_t)(n0 + w * 8 * NC + lgrp) * 768 + gg * 8;
    u16* lba = As + w * 32 * 64;
    u16* lbb = Bs + w * 8 * NC * 64;

    const int l15 = lane & 15, qg = lane >> 4, q4 = qg * 4;

    int aoff[4][2], boff[NC][2];
#pragma unroll
    for (int r = 0; r < 4; ++r) {
        int row = 64 * wm + 16 * r + l15;
#pragma unroll
        for (int kc = 0; kc < 2; ++kc)
            aoff[r][kc] = row * 64 + (((4 * kc + qg) ^ (row & 7)) << 3);
    }
#pragma unroll
    for (int c = 0; c < NC; ++c) {
        int row = 16 * NC * wn + 16 * c + l15;
#pragma unroll
        for (int kc = 0; kc < 2; ++kc)
            boff[c][kc] = row * 64 + (((4 * kc + qg) ^ (row & 7)) << 3);
    }

    f32x4 acc[4][NC] = {};

    for (int k0 = 0; k0 < 768; k0 += 64) {
#pragma unroll
        for (int i = 0; i < 4; ++i)
            async_cp16(ga + (size_t)i * 8 * 768 + k0, lba + i * 512);
#pragma unroll
        for (int i = 0; i < NC; ++i)
            async_cp16(gb + (size_t)i * 8 * 768 + k0, lbb + i * 512);
        __syncthreads();
#pragma unroll
        for (int kc = 0; kc < 2; ++kc) {
            bf16x8 af[4], bfr[NC];
#pragma unroll
            for (int r = 0; r < 4; ++r) af[r] = *(const bf16x8*)&As[aoff[r][kc]];
#pragma unroll
            for (int c = 0; c < NC; ++c) bfr[c] = *(const bf16x8*)&Bs[boff[c][kc]];
#pragma unroll
            for (int r = 0; r < 4; ++r)
#pragma unroll
                for (int c = 0; c < NC; ++c)
                    acc[r][c] = __builtin_amdgcn_mfma_f32_16x16x32_bf16(af[r], bfr[c], acc[r][c], 0, 0, 0);
        }
        __syncthreads();
    }

#pragma unroll
    for (int r = 0; r < 4; ++r) {
#pragma unroll
        for (int c = 0; c < NC; ++c) {
            const int cg = n0 + 16 * NC * wn + 16 * c + l15;
            const float bv = bias[cg];
            const int mb = m0 + 64 * wm + 16 * r + q4;
            if constexpr (EPI == 0) {
#pragma unroll
                for (int g = 0; g < 4; ++g)
                    outf[(size_t)(mb + g) * DIM + cg] = acc[r][c][g] + bv;
            } else {
                const int which = (cg >= 1536) ? 2 : (cg >= 768 ? 1 : 0);
                const int rem = cg - which * 768;
                const int h = rem >> 6, d = rem & 63;
                const int b = mb >> 10, q = mb & 1023;
                if (which == 0) {
#pragma unroll
                    for (int g = 0; g < 4; ++g)
                        outq[QOFF + ((size_t)(b * NH + h) * SEQ + q + g) * HD + d] =
                            f2bf((acc[r][c][g] + bv) * QSCALE);
                } else if (which == 1) {
#pragma unroll
                    for (int g = 0; g < 4; ++g)
                        outq[KOFF + ((size_t)(b * NH + h) * SEQ + q + g) * HD + d] =
                            f2bf(acc[r][c][g] + bv);
                } else {
                    ushort4 pk;
                    pk.x = f2bf(acc[r][c][0] + bv); pk.y = f2bf(acc[r][c][1] + bv);
                    pk.z = f2bf(acc[r][c][2] + bv); pk.w = f2bf(acc[r][c][3] + bv);
                    *(ushort4*)&outq[VOFF + ((size_t)(b * NH + h) * HD + d) * SEQ + q] = pk;
                }
            }
        }
    }
}

// ---- Flash attention v4 (R0-byte-exact).
// St = K·Q^T via 16x16x32 (A=K LDS, B=Q regs) -> C-layout col=q=l15, row=key=qg*4+reg,
// which IS the 16x16x16 B-operand layout -> PV directly from regs.
// K,V async dbuf staging; ONE barrier per kt-tile.
__global__ __launch_bounds__(256) void flash_attn(const u16* __restrict__ ws, u16* __restrict__ attn_out) {
    __shared__ __align__(16) u16 Ks[2][64 * 64];
    __shared__ __align__(16) u16 Vs[2][64 * 64];

    const int tid = threadIdx.x;
    const int lane = tid & 63;
    const int wv = tid >> 6;
    const int qt = blockIdx.x;   // 0..7
    const int bh = blockIdx.y;   // 0..95
    const u16* qp = ws + QOFF + (size_t)bh * SEQ * HD;
    const u16* kp = ws + KOFF + (size_t)bh * SEQ * HD;
    const u16* vp = ws + VOFF + (size_t)bh * HD * SEQ;

    const int l15 = lane & 15, qg = lane >> 4, q8 = qg * 8;
    const int l7 = l15 & 7;

    bf16x8 bq[2][2];
#pragma unroll
    for (int r = 0; r < 2; ++r)
#pragma unroll
        for (int kc = 0; kc < 2; ++kc)
            bq[r][kc] = *(const bf16x8*)&qp[(size_t)(qt * 128 + 32 * wv + 16 * r + l15) * HD + 32 * kc + q8];

    const int lgrp = lane >> 3;
    const int gg = (lane & 7) ^ lgrp;
    auto stage = [&](int buf, int ktv) {
#pragma unroll
        for (int i = 0; i < 2; ++i) {
            async_cp16(kp + (size_t)(ktv * 64 + wv * 16 + i * 8 + lgrp) * 64 + gg * 8,
                       &Ks[buf][(wv * 16 + i * 8) * 64]);
            async_cp16(vp + (size_t)(wv * 16 + i * 8 + lgrp) * SEQ + ktv * 64 + gg * 8,
                       &Vs[buf][(wv * 16 + i * 8) * 64]);
        }
    };
    stage(0, 0);

    int akoff[4][2], avoff[4][4];
#pragma unroll
    for (int c = 0; c < 4; ++c) {
#pragma unroll
        for (int kc = 0; kc < 2; ++kc)
            akoff[c][kc] = (16 * c + l15) * 64 + (((4 * kc + qg) ^ l7) << 3);
#pragma unroll
        for (int cd = 0; cd < 4; ++cd)
            avoff[c][cd] = (16 * cd + l15) * 64 + (((2 * c + (qg >> 1)) ^ l7) << 3) + (qg & 1) * 4;
    }

    f32x4 oacc[2][4] = {};   // O^T: D col=q=l15, row=d=16cd+qg*4+reg
    float lsum[2] = {0.f, 0.f};

    for (int kt = 0; kt < 16; ++kt) {
        const int cur = kt & 1;
        WAIT_VM0;
        BAR;
        CFENCE;
        if (kt < 15) stage(cur ^ 1, kt + 1);

        f32x4 sacc[4][2] = {};
#pragma unroll
        for (int c = 0; c < 4; ++c) {
#pragma unroll
            for (int kc = 0; kc < 2; ++kc) {
                bf16x8 ak = *(const bf16x8*)&Ks[cur][akoff[c][kc]];
#pragma unroll
                for (int r = 0; r < 2; ++r)
                    sacc[c][r] = __builtin_amdgcn_mfma_f32_16x16x32_bf16(ak, bq[r][kc], sacc[c][r], 0, 0, 0);
            }
        }

        s16x4 pf[4][2];
#pragma unroll
        for (int c = 0; c < 4; ++c) {
#pragma unroll
            for (int r = 0; r < 2; ++r) {
                float p0 = __builtin_amdgcn_exp2f(sacc[c][r][0]);
                float p1 = __builtin_amdgcn_exp2f(sacc[c][r][1]);
                float p2 = __builtin_amdgcn_exp2f(sacc[c][r][2]);
                float p3 = __builtin_amdgcn_exp2f(sacc[c][r][3]);
                lsum[r] += (p0 + p1) + (p2 + p3);
                union { uint2 u; s16x4 v; } pk;
                pk.u.x = pkbf(p0, p1); pk.u.y = pkbf(p2, p3);
                pf[c][r] = pk.v;
            }
        }

#pragma unroll
        for (int c = 0; c < 4; ++c) {
            s16x4 av[4];
#pragma unroll
            for (int cd = 0; cd < 4; ++cd)
                av[cd] = *(const s16x4*)&Vs[cur][avoff[c][cd]];
#pragma unroll
            for (int r = 0; r < 2; ++r)
#pragma unroll
                for (int cd = 0; cd < 4; ++cd)
                    oacc[r][cd] = __builtin_amdgcn_mfma_f32_16x16x16bf16_1k(av[cd], pf[c][r], oacc[r][cd], 0, 0, 0);
        }
    }

#pragma unroll
    for (int r = 0; r < 2; ++r) {
        lsum[r] += __shfl_xor(lsum[r], 16);
        lsum[r] += __shfl_xor(lsum[r], 32);
    }

    const int b = bh / NH, h = bh % NH;
#pragma unroll
    for (int r = 0; r < 2; ++r) {
        const float inv = 1.f / lsum[r];
        const int qrow = qt * 128 + 32 * wv + 16 * r + l15;
        u16* orow = attn_out + (size_t)(b * SEQ + qrow) * DIM + h * HD + qg * 4;
#pragma unroll
        for (int cd = 0; cd < 4; ++cd) {
            ushort4 o;
            o.x = f2bf(oacc[r][cd][0] * inv); o.y = f2bf(oacc[r][cd][1] * inv);
            o.z = f2bf(oacc[r][cd][2] * inv); o.w = f2bf(oacc[r][cd][3] * inv);
            *(ushort4*)&orow[16 * cd] = o;
        }
    }
}

extern "C" void kernel_launch(void* const* d_in, const int* in_sizes, int n_in,
                              void* d_out, int out_size, void* d_ws, size_t ws_size,
                              hipStream_t stream) {
    const float* x      = (const float*)d_in[0];
    const float* w_qkv  = (const float*)d_in[1];
    const float* b_qkv  = (const float*)d_in[2];
    const float* w_proj = (const float*)d_in[3];
    const float* b_proj = (const float*)d_in[4];
    float* out = (float*)d_out;
    u16* ws = (u16*)d_ws;

    prep<<<3648, 256, 0, stream>>>(x, w_qkv, w_proj, ws);
    gemm512<1><<<dim3(18, 64), 512, 0, stream>>>(ws + XOFF, ws + WQOFF, b_qkv, nullptr, ws);
    flash_attn<<<dim3(8, 96), 256, 0, stream>>>(ws, ws + AOFF);
    gemm256<0, 2><<<dim3(12, 64), 256, 0, stream>>>(ws + AOFF, ws + WPOFF, b_proj, out, nullptr);
}

// Round 6
// 197.012 us; speedup vs baseline: 1.0777x; 1.0777x over previous
//
#include <hip/hip_runtime.h>
#include <cstdint>

#define DIM 768
#define NH 12
#define HD 64
#define SEQ 1024
#define NBH 96

// ws layout (u16 elements)
#define QOFF  ((size_t)0)
#define KOFF  ((size_t)6291456)
#define VOFF  ((size_t)12582912)
#define AOFF  ((size_t)18874368)   // attn output bf16 [8192][768]
#define XOFF  ((size_t)25165824)   // x bf16
#define WQOFF ((size_t)31457280)   // w_qkv^T bf16 [2304][768]
#define WPOFF ((size_t)33226752)   // w_proj^T bf16 [768][768]

#define QSCALE 0.18033688f  /* 0.125 * log2(e) */

// s_waitcnt immediates: vmcnt[3:0]@[3:0], expcnt@[6:4], lgkmcnt@[11:8], vmcnt[5:4]@[15:14]
#define WAIT_VM0   __builtin_amdgcn_s_waitcnt(0x0F70)  /* vmcnt(0) only  */
#define BAR        __builtin_amdgcn_s_barrier()
#define CFENCE     __asm__ __volatile__("" ::: "memory")

typedef __attribute__((ext_vector_type(8))) __bf16 bf16x8;
typedef __attribute__((ext_vector_type(2))) __bf16 bf16x2;
typedef __attribute__((ext_vector_type(4))) float f32x4;
typedef __attribute__((ext_vector_type(4))) short s16x4;
typedef unsigned short u16;

__device__ __forceinline__ u16 f2bf(float f) {
    union { float f; unsigned u; } x; x.f = f;
    unsigned r = x.u + 0x7fffu + ((x.u >> 16) & 1u);
    return (u16)(r >> 16);
}

__device__ __forceinline__ unsigned pkbf(float a, float b) {
#if __has_builtin(__builtin_amdgcn_cvt_pk_bf16_f32)
    bf16x2 v = __builtin_amdgcn_cvt_pk_bf16_f32(a, b);
    union { bf16x2 v; unsigned u; } c; c.v = v; return c.u;
#else
    return (unsigned)f2bf(a) | ((unsigned)f2bf(b) << 16);
#endif
}

__device__ __forceinline__ void async_cp16(const void* g, void* l) {
    __builtin_amdgcn_global_load_lds((const __attribute__((address_space(1))) void*)g,
                                     (__attribute__((address_space(3))) void*)l, 16, 0, 0);
}

// ---- fused prep: x fp32->bf16 (2 float4/thread), plus both weight transposes
__global__ __launch_bounds__(256) void prep(const float* __restrict__ x,
                                            const float* __restrict__ wq,
                                            const float* __restrict__ wp,
                                            u16* __restrict__ ws) {
    const int bid = blockIdx.x;
    const int tid = threadIdx.x;
    if (bid < 3072) {
        size_t i = (size_t)bid * 512 + tid;
#pragma unroll
        for (int j = 0; j < 2; ++j, i += 256) {
            float4 v = *(const float4*)&x[i * 4];
            ushort4 o;
            o.x = f2bf(v.x); o.y = f2bf(v.y); o.z = f2bf(v.z); o.w = f2bf(v.w);
            *(ushort4*)&ws[XOFF + i * 4] = o;
        }
        return;
    }
    __shared__ float T[64][65];
    const float* w; u16* wt; int N, bx, by;
    if (bid < 3504) { int b = bid - 3072; w = wq; wt = ws + WQOFF; N = 2304; bx = b % 36; by = b / 36; }
    else            { int b = bid - 3504; w = wp; wt = ws + WPOFF; N = 768;  bx = b % 12; by = b / 12; }
    const int K = 768;
    const int k0 = by * 64, n0 = bx * 64;
    const int r = tid >> 4, c4 = (tid & 15) * 4;
#pragma unroll
    for (int i = 0; i < 4; ++i) {
        float4 v = *(const float4*)&w[(size_t)(k0 + r + 16 * i) * N + n0 + c4];
        T[r + 16 * i][c4 + 0] = v.x; T[r + 16 * i][c4 + 1] = v.y;
        T[r + 16 * i][c4 + 2] = v.z; T[r + 16 * i][c4 + 3] = v.w;
    }
    __syncthreads();
#pragma unroll
    for (int i = 0; i < 4; ++i) {
        int rr = r + 16 * i;
        ushort4 o;
        o.x = f2bf(T[c4 + 0][rr]); o.y = f2bf(T[c4 + 1][rr]);
        o.z = f2bf(T[c4 + 2][rr]); o.w = f2bf(T[c4 + 3][rr]);
        *(ushort4*)&wt[(size_t)(n0 + rr) * K + k0 + c4] = o;
    }
}

// ---- GEMM, R3 single-buffer structure, parametric N-tile.
// Tile = 128m x (32*NC)n, BK=64, global_load_lds w=16, XOR-8 swizzle.
// Fragment loads split per-kc (live frags 32 VGPR not 64) + launch_bounds(256,3)
// to fit 3 waves/SIMD (VGPR+AGPR <= 170).
// EPI=0: out fp32 [M][768] + bias.  EPI=1: qkv scatter (Q prescaled, V transposed).
template <int EPI, int NC>
__global__ __launch_bounds__(256, 3) void gemm_bt(const u16* __restrict__ A,
                                                  const u16* __restrict__ Bt,
                                                  const float* __restrict__ bias,
                                                  float* __restrict__ outf,
                                                  u16* __restrict__ outq) {
    __shared__ __align__(16) u16 As[128 * 64];
    __shared__ __align__(16) u16 Bs[32 * NC * 64];
    const int tid = threadIdx.x;
    const int lane = tid & 63;
    const int w = tid >> 6;
    const int wm = w >> 1, wn = w & 1;
    const int m0 = blockIdx.y * 128, n0 = blockIdx.x * (32 * NC);

    const int lgrp = lane >> 3;             // row-within-8
    const int gg = (lane & 7) ^ lgrp;       // swizzled global k-group for staging
    const u16* ga = A  + (size_t)(m0 + w * 32 + lgrp) * 768 + gg * 8;
    const u16* gb = Bt + (size_t)(n0 + w * 8 * NC + lgrp) * 768 + gg * 8;
    u16* lba = As + w * 32 * 64;
    u16* lbb = Bs + w * 8 * NC * 64;

    const int l15 = lane & 15, qg = lane >> 4, q4 = qg * 4;

    int aoff[4][2], boff[NC][2];
#pragma unroll
    for (int r = 0; r < 4; ++r) {
        int row = 64 * wm + 16 * r + l15;
#pragma unroll
        for (int kc = 0; kc < 2; ++kc)
            aoff[r][kc] = row * 64 + (((4 * kc + qg) ^ (row & 7)) << 3);
    }
#pragma unroll
    for (int c = 0; c < NC; ++c) {
        int row = 16 * NC * wn + 16 * c + l15;
#pragma unroll
        for (int kc = 0; kc < 2; ++kc)
            boff[c][kc] = row * 64 + (((4 * kc + qg) ^ (row & 7)) << 3);
    }

    f32x4 acc[4][NC] = {};

    for (int k0 = 0; k0 < 768; k0 += 64) {
#pragma unroll
        for (int i = 0; i < 4; ++i)
            async_cp16(ga + (size_t)i * 8 * 768 + k0, lba + i * 512);
#pragma unroll
        for (int i = 0; i < NC; ++i)
            async_cp16(gb + (size_t)i * 8 * 768 + k0, lbb + i * 512);
        __syncthreads();
#pragma unroll
        for (int kc = 0; kc < 2; ++kc) {
            bf16x8 af[4], bfr[NC];
#pragma unroll
            for (int r = 0; r < 4; ++r) af[r] = *(const bf16x8*)&As[aoff[r][kc]];
#pragma unroll
            for (int c = 0; c < NC; ++c) bfr[c] = *(const bf16x8*)&Bs[boff[c][kc]];
#pragma unroll
            for (int r = 0; r < 4; ++r)
#pragma unroll
                for (int c = 0; c < NC; ++c)
                    acc[r][c] = __builtin_amdgcn_mfma_f32_16x16x32_bf16(af[r], bfr[c], acc[r][c], 0, 0, 0);
        }
        __syncthreads();
    }

#pragma unroll
    for (int r = 0; r < 4; ++r) {
#pragma unroll
        for (int c = 0; c < NC; ++c) {
            const int cg = n0 + 16 * NC * wn + 16 * c + l15;
            const float bv = bias[cg];
            const int mb = m0 + 64 * wm + 16 * r + q4;
            if constexpr (EPI == 0) {
#pragma unroll
                for (int g = 0; g < 4; ++g)
                    outf[(size_t)(mb + g) * DIM + cg] = acc[r][c][g] + bv;
            } else {
                const int which = (cg >= 1536) ? 2 : (cg >= 768 ? 1 : 0);  // uniform over l15
                const int rem = cg - which * 768;
                const int h = rem >> 6, d = rem & 63;
                const int b = mb >> 10, q = mb & 1023;
                if (which == 0) {
#pragma unroll
                    for (int g = 0; g < 4; ++g)
                        outq[QOFF + ((size_t)(b * NH + h) * SEQ + q + g) * HD + d] =
                            f2bf((acc[r][c][g] + bv) * QSCALE);
                } else if (which == 1) {
#pragma unroll
                    for (int g = 0; g < 4; ++g)
                        outq[KOFF + ((size_t)(b * NH + h) * SEQ + q + g) * HD + d] =
                            f2bf(acc[r][c][g] + bv);
                } else {
                    ushort4 pk;
                    pk.x = f2bf(acc[r][c][0] + bv); pk.y = f2bf(acc[r][c][1] + bv);
                    pk.z = f2bf(acc[r][c][2] + bv); pk.w = f2bf(acc[r][c][3] + bv);
                    *(ushort4*)&outq[VOFF + ((size_t)(b * NH + h) * HD + d) * SEQ + q] = pk;
                }
            }
        }
    }
}

// ---- Flash attention v4 (unchanged): P never touches LDS.
// St = K·Q^T via 16x16x32 (A=K LDS, B=Q regs) -> C-layout col=q=l15, row=key=qg*4+reg,
// which IS the 16x16x16 B-operand layout -> PV directly from regs.
// K,V async dbuf staging; ONE barrier per kt-tile.
__global__ __launch_bounds__(256) void flash_attn(const u16* __restrict__ ws, u16* __restrict__ attn_out) {
    __shared__ __align__(16) u16 Ks[2][64 * 64];
    __shared__ __align__(16) u16 Vs[2][64 * 64];

    const int tid = threadIdx.x;
    const int lane = tid & 63;
    const int wv = tid >> 6;
    const int qt = blockIdx.x;   // 0..7
    const int bh = blockIdx.y;   // 0..95
    const u16* qp = ws + QOFF + (size_t)bh * SEQ * HD;
    const u16* kp = ws + KOFF + (size_t)bh * SEQ * HD;
    const u16* vp = ws + VOFF + (size_t)bh * HD * SEQ;

    const int l15 = lane & 15, qg = lane >> 4, q8 = qg * 8;
    const int l7 = l15 & 7;

    bf16x8 bq[2][2];
#pragma unroll
    for (int r = 0; r < 2; ++r)
#pragma unroll
        for (int kc = 0; kc < 2; ++kc)
            bq[r][kc] = *(const bf16x8*)&qp[(size_t)(qt * 128 + 32 * wv + 16 * r + l15) * HD + 32 * kc + q8];

    const int lgrp = lane >> 3;
    const int gg = (lane & 7) ^ lgrp;
    auto stage = [&](int buf, int ktv) {
#pragma unroll
        for (int i = 0; i < 2; ++i) {
            async_cp16(kp + (size_t)(ktv * 64 + wv * 16 + i * 8 + lgrp) * 64 + gg * 8,
                       &Ks[buf][(wv * 16 + i * 8) * 64]);
            async_cp16(vp + (size_t)(wv * 16 + i * 8 + lgrp) * SEQ + ktv * 64 + gg * 8,
                       &Vs[buf][(wv * 16 + i * 8) * 64]);
        }
    };
    stage(0, 0);

    int akoff[4][2], avoff[4][4];
#pragma unroll
    for (int c = 0; c < 4; ++c) {
#pragma unroll
        for (int kc = 0; kc < 2; ++kc)
            akoff[c][kc] = (16 * c + l15) * 64 + (((4 * kc + qg) ^ l7) << 3);
#pragma unroll
        for (int cd = 0; cd < 4; ++cd)
            avoff[c][cd] = (16 * cd + l15) * 64 + (((2 * c + (qg >> 1)) ^ l7) << 3) + (qg & 1) * 4;
    }

    f32x4 oacc[2][4] = {};   // O^T: D col=q=l15, row=d=16cd+qg*4+reg
    float lsum[2] = {0.f, 0.f};

    for (int kt = 0; kt < 16; ++kt) {
        const int cur = kt & 1;
        WAIT_VM0;
        BAR;
        CFENCE;
        if (kt < 15) stage(cur ^ 1, kt + 1);

        f32x4 sacc[4][2] = {};
#pragma unroll
        for (int c = 0; c < 4; ++c) {
#pragma unroll
            for (int kc = 0; kc < 2; ++kc) {
                bf16x8 ak = *(const bf16x8*)&Ks[cur][akoff[c][kc]];
#pragma unroll
                for (int r = 0; r < 2; ++r)
                    sacc[c][r] = __builtin_amdgcn_mfma_f32_16x16x32_bf16(ak, bq[r][kc], sacc[c][r], 0, 0, 0);
            }
        }

        s16x4 pf[4][2];
#pragma unroll
        for (int c = 0; c < 4; ++c) {
#pragma unroll
            for (int r = 0; r < 2; ++r) {
                float p0 = __builtin_amdgcn_exp2f(sacc[c][r][0]);
                float p1 = __builtin_amdgcn_exp2f(sacc[c][r][1]);
                float p2 = __builtin_amdgcn_exp2f(sacc[c][r][2]);
                float p3 = __builtin_amdgcn_exp2f(sacc[c][r][3]);
                lsum[r] += (p0 + p1) + (p2 + p3);
                union { uint2 u; s16x4 v; } pk;
                pk.u.x = pkbf(p0, p1); pk.u.y = pkbf(p2, p3);
                pf[c][r] = pk.v;
            }
        }

#pragma unroll
        for (int c = 0; c < 4; ++c) {
            s16x4 av[4];
#pragma unroll
            for (int cd = 0; cd < 4; ++cd)
                av[cd] = *(const s16x4*)&Vs[cur][avoff[c][cd]];
#pragma unroll
            for (int r = 0; r < 2; ++r)
#pragma unroll
                for (int cd = 0; cd < 4; ++cd)
                    oacc[r][cd] = __builtin_amdgcn_mfma_f32_16x16x16bf16_1k(av[cd], pf[c][r], oacc[r][cd], 0, 0, 0);
        }
    }

#pragma unroll
    for (int r = 0; r < 2; ++r) {
        lsum[r] += __shfl_xor(lsum[r], 16);
        lsum[r] += __shfl_xor(lsum[r], 32);
    }

    const int b = bh / NH, h = bh % NH;
#pragma unroll
    for (int r = 0; r < 2; ++r) {
        const float inv = 1.f / lsum[r];
        const int qrow = qt * 128 + 32 * wv + 16 * r + l15;
        u16* orow = attn_out + (size_t)(b * SEQ + qrow) * DIM + h * HD + qg * 4;
#pragma unroll
        for (int cd = 0; cd < 4; ++cd) {
            ushort4 o;
            o.x = f2bf(oacc[r][cd][0] * inv); o.y = f2bf(oacc[r][cd][1] * inv);
            o.z = f2bf(oacc[r][cd][2] * inv); o.w = f2bf(oacc[r][cd][3] * inv);
            *(ushort4*)&orow[16 * cd] = o;
        }
    }
}

extern "C" void kernel_launch(void* const* d_in, const int* in_sizes, int n_in,
                              void* d_out, int out_size, void* d_ws, size_t ws_size,
                              hipStream_t stream) {
    const float* x      = (const float*)d_in[0];
    const float* w_qkv  = (const float*)d_in[1];
    const float* b_qkv  = (const float*)d_in[2];
    const float* w_proj = (const float*)d_in[3];
    const float* b_proj = (const float*)d_in[4];
    float* out = (float*)d_out;
    u16* ws = (u16*)d_ws;

    prep<<<3648, 256, 0, stream>>>(x, w_qkv, w_proj, ws);
    gemm_bt<1, 4><<<dim3(18, 64), 256, 0, stream>>>(ws + XOFF, ws + WQOFF, b_qkv, nullptr, ws);
    flash_attn<<<dim3(8, 96), 256, 0, stream>>>(ws, ws + AOFF);
    gemm_bt<0, 2><<<dim3(12, 64), 256, 0, stream>>>(ws + AOFF, ws + WPOFF, b_proj, out, nullptr);
}

// Round 7
// 194.442 us; speedup vs baseline: 1.0920x; 1.0132x over previous
//
#include <hip/hip_runtime.h>
#include <cstdint>

#define DIM 768
#define NH 12
#define HD 64
#define SEQ 1024
#define NBH 96

// ws layout (u16 elements)
#define QOFF  ((size_t)0)
#define KOFF  ((size_t)6291456)
#define VOFF  ((size_t)12582912)
#define AOFF  ((size_t)18874368)   // attn output bf16 [8192][768]
#define XOFF  ((size_t)25165824)   // x bf16
#define WQOFF ((size_t)31457280)   // w_qkv^T bf16 [2304][768]
#define WPOFF ((size_t)33226752)   // w_proj^T bf16 [768][768]

#define QSCALE 0.18033688f  /* 0.125 * log2(e) */

// s_waitcnt immediates: vmcnt[3:0]@[3:0], expcnt@[6:4], lgkmcnt@[11:8], vmcnt[5:4]@[15:14]
#define WAIT_VM0   __builtin_amdgcn_s_waitcnt(0x0F70)  /* vmcnt(0) only  */
#define BAR        __builtin_amdgcn_s_barrier()
#define CFENCE     __asm__ __volatile__("" ::: "memory")

typedef __attribute__((ext_vector_type(8))) __bf16 bf16x8;
typedef __attribute__((ext_vector_type(2))) __bf16 bf16x2;
typedef __attribute__((ext_vector_type(4))) float f32x4;
typedef __attribute__((ext_vector_type(4))) short s16x4;
typedef unsigned short u16;

__device__ __forceinline__ u16 f2bf(float f) {
    union { float f; unsigned u; } x; x.f = f;
    unsigned r = x.u + 0x7fffu + ((x.u >> 16) & 1u);
    return (u16)(r >> 16);
}

__device__ __forceinline__ unsigned pkbf(float a, float b) {
#if __has_builtin(__builtin_amdgcn_cvt_pk_bf16_f32)
    bf16x2 v = __builtin_amdgcn_cvt_pk_bf16_f32(a, b);
    union { bf16x2 v; unsigned u; } c; c.v = v; return c.u;
#else
    return (unsigned)f2bf(a) | ((unsigned)f2bf(b) << 16);
#endif
}

__device__ __forceinline__ void async_cp16(const void* g, void* l) {
    __builtin_amdgcn_global_load_lds((const __attribute__((address_space(1))) void*)g,
                                     (__attribute__((address_space(3))) void*)l, 16, 0, 0);
}

// ---- fused prep: x fp32->bf16 (2 float4/thread), plus both weight transposes
__global__ __launch_bounds__(256) void prep(const float* __restrict__ x,
                                            const float* __restrict__ wq,
                                            const float* __restrict__ wp,
                                            u16* __restrict__ ws) {
    const int bid = blockIdx.x;
    const int tid = threadIdx.x;
    if (bid < 3072) {
        size_t i = (size_t)bid * 512 + tid;
#pragma unroll
        for (int j = 0; j < 2; ++j, i += 256) {
            float4 v = *(const float4*)&x[i * 4];
            ushort4 o;
            o.x = f2bf(v.x); o.y = f2bf(v.y); o.z = f2bf(v.z); o.w = f2bf(v.w);
            *(ushort4*)&ws[XOFF + i * 4] = o;
        }
        return;
    }
    __shared__ float T[64][65];
    const float* w; u16* wt; int N, bx, by;
    if (bid < 3504) { int b = bid - 3072; w = wq; wt = ws + WQOFF; N = 2304; bx = b % 36; by = b / 36; }
    else            { int b = bid - 3504; w = wp; wt = ws + WPOFF; N = 768;  bx = b % 12; by = b / 12; }
    const int K = 768;
    const int k0 = by * 64, n0 = bx * 64;
    const int r = tid >> 4, c4 = (tid & 15) * 4;
#pragma unroll
    for (int i = 0; i < 4; ++i) {
        float4 v = *(const float4*)&w[(size_t)(k0 + r + 16 * i) * N + n0 + c4];
        T[r + 16 * i][c4 + 0] = v.x; T[r + 16 * i][c4 + 1] = v.y;
        T[r + 16 * i][c4 + 2] = v.z; T[r + 16 * i][c4 + 3] = v.w;
    }
    __syncthreads();
#pragma unroll
    for (int i = 0; i < 4; ++i) {
        int rr = r + 16 * i;
        ushort4 o;
        o.x = f2bf(T[c4 + 0][rr]); o.y = f2bf(T[c4 + 1][rr]);
        o.z = f2bf(T[c4 + 2][rr]); o.w = f2bf(T[c4 + 3][rr]);
        *(ushort4*)&wt[(size_t)(n0 + rr) * K + k0 + c4] = o;
    }
}

// ---- GEMM, R0 single-buffer structure, parametric N-tile (unchanged).
// Tile = 128m x (32*NC)n, BK=64, global_load_lds w=16, XOR-8 swizzle.
// EPI=0: out fp32 [M][768] + bias.  EPI=1: qkv scatter (Q prescaled, V transposed).
template <int EPI, int NC>
__global__ __launch_bounds__(256, 3) void gemm_bt(const u16* __restrict__ A,
                                                  const u16* __restrict__ Bt,
                                                  const float* __restrict__ bias,
                                                  float* __restrict__ outf,
                                                  u16* __restrict__ outq) {
    __shared__ __align__(16) u16 As[128 * 64];
    __shared__ __align__(16) u16 Bs[32 * NC * 64];
    const int tid = threadIdx.x;
    const int lane = tid & 63;
    const int w = tid >> 6;
    const int wm = w >> 1, wn = w & 1;
    const int m0 = blockIdx.y * 128, n0 = blockIdx.x * (32 * NC);

    const int lgrp = lane >> 3;             // row-within-8
    const int gg = (lane & 7) ^ lgrp;       // swizzled global k-group for staging
    const u16* ga = A  + (size_t)(m0 + w * 32 + lgrp) * 768 + gg * 8;
    const u16* gb = Bt + (size_t)(n0 + w * 8 * NC + lgrp) * 768 + gg * 8;
    u16* lba = As + w * 32 * 64;
    u16* lbb = Bs + w * 8 * NC * 64;

    const int l15 = lane & 15, qg = lane >> 4, q4 = qg * 4;

    int aoff[4][2], boff[NC][2];
#pragma unroll
    for (int r = 0; r < 4; ++r) {
        int row = 64 * wm + 16 * r + l15;
#pragma unroll
        for (int kc = 0; kc < 2; ++kc)
            aoff[r][kc] = row * 64 + (((4 * kc + qg) ^ (row & 7)) << 3);
    }
#pragma unroll
    for (int c = 0; c < NC; ++c) {
        int row = 16 * NC * wn + 16 * c + l15;
#pragma unroll
        for (int kc = 0; kc < 2; ++kc)
            boff[c][kc] = row * 64 + (((4 * kc + qg) ^ (row & 7)) << 3);
    }

    f32x4 acc[4][NC] = {};

    for (int k0 = 0; k0 < 768; k0 += 64) {
#pragma unroll
        for (int i = 0; i < 4; ++i)
            async_cp16(ga + (size_t)i * 8 * 768 + k0, lba + i * 512);
#pragma unroll
        for (int i = 0; i < NC; ++i)
            async_cp16(gb + (size_t)i * 8 * 768 + k0, lbb + i * 512);
        __syncthreads();
#pragma unroll
        for (int kc = 0; kc < 2; ++kc) {
            bf16x8 af[4], bfr[NC];
#pragma unroll
            for (int r = 0; r < 4; ++r) af[r] = *(const bf16x8*)&As[aoff[r][kc]];
#pragma unroll
            for (int c = 0; c < NC; ++c) bfr[c] = *(const bf16x8*)&Bs[boff[c][kc]];
#pragma unroll
            for (int r = 0; r < 4; ++r)
#pragma unroll
                for (int c = 0; c < NC; ++c)
                    acc[r][c] = __builtin_amdgcn_mfma_f32_16x16x32_bf16(af[r], bfr[c], acc[r][c], 0, 0, 0);
        }
        __syncthreads();
    }

#pragma unroll
    for (int r = 0; r < 4; ++r) {
#pragma unroll
        for (int c = 0; c < NC; ++c) {
            const int cg = n0 + 16 * NC * wn + 16 * c + l15;
            const float bv = bias[cg];
            const int mb = m0 + 64 * wm + 16 * r + q4;
            if constexpr (EPI == 0) {
#pragma unroll
                for (int g = 0; g < 4; ++g)
                    outf[(size_t)(mb + g) * DIM + cg] = acc[r][c][g] + bv;
            } else {
                const int which = (cg >= 1536) ? 2 : (cg >= 768 ? 1 : 0);  // uniform over l15
                const int rem = cg - which * 768;
                const int h = rem >> 6, d = rem & 63;
                const int b = mb >> 10, q = mb & 1023;
                if (which == 0) {
#pragma unroll
                    for (int g = 0; g < 4; ++g)
                        outq[QOFF + ((size_t)(b * NH + h) * SEQ + q + g) * HD + d] =
                            f2bf((acc[r][c][g] + bv) * QSCALE);
                } else if (which == 1) {
#pragma unroll
                    for (int g = 0; g < 4; ++g)
                        outq[KOFF + ((size_t)(b * NH + h) * SEQ + q + g) * HD + d] =
                            f2bf(acc[r][c][g] + bv);
                } else {
                    ushort4 pk;
                    pk.x = f2bf(acc[r][c][0] + bv); pk.y = f2bf(acc[r][c][1] + bv);
                    pk.z = f2bf(acc[r][c][2] + bv); pk.w = f2bf(acc[r][c][3] + bv);
                    *(ushort4*)&outq[VOFF + ((size_t)(b * NH + h) * HD + d) * SEQ + q] = pk;
                }
            }
        }
    }
}

// ---- Flash attention v5: 8-wave blocks (512 thr), 16 q-rows/wave.
// Single change vs R0/v4: the per-wave r=2 row-pair dimension is removed and the
// freed parallelism doubles waves/CU (12 -> 24) to saturate the VALU-bound softmax
// (VALUBusy was 49.7% at 3 blocks x 4 waves/CU). Same grid (8,96), same 32 KB LDS,
// same K/V staging totals & XOR-8 swizzle, same MFMA layout trick (P never in LDS).
__global__ __launch_bounds__(512) void flash_attn(const u16* __restrict__ ws, u16* __restrict__ attn_out) {
    __shared__ __align__(16) u16 Ks[2][64 * 64];
    __shared__ __align__(16) u16 Vs[2][64 * 64];

    const int tid = threadIdx.x;
    const int lane = tid & 63;
    const int wv = tid >> 6;     // 0..7
    const int qt = blockIdx.x;   // 0..7
    const int bh = blockIdx.y;   // 0..95
    const u16* qp = ws + QOFF + (size_t)bh * SEQ * HD;
    const u16* kp = ws + KOFF + (size_t)bh * SEQ * HD;
    const u16* vp = ws + VOFF + (size_t)bh * HD * SEQ;

    const int l15 = lane & 15, qg = lane >> 4, q8 = qg * 8;
    const int l7 = l15 & 7;

    // one 16-row q-group per wave
    bf16x8 bq[2];
#pragma unroll
    for (int kc = 0; kc < 2; ++kc)
        bq[kc] = *(const bf16x8*)&qp[(size_t)(qt * 128 + 16 * wv + l15) * HD + 32 * kc + q8];

    const int lgrp = lane >> 3;
    const int gg = (lane & 7) ^ lgrp;
    // 8 waves: each stages 8 rows of K and 8 rows of V (1 cp16 each)
    auto stage = [&](int buf, int ktv) {
        async_cp16(kp + (size_t)(ktv * 64 + wv * 8 + lgrp) * 64 + gg * 8,
                   &Ks[buf][(wv * 8) * 64]);
        async_cp16(vp + (size_t)(wv * 8 + lgrp) * SEQ + ktv * 64 + gg * 8,
                   &Vs[buf][(wv * 8) * 64]);
    };
    stage(0, 0);

    int akoff[4][2], avoff[4][4];
#pragma unroll
    for (int c = 0; c < 4; ++c) {
#pragma unroll
        for (int kc = 0; kc < 2; ++kc)
            akoff[c][kc] = (16 * c + l15) * 64 + (((4 * kc + qg) ^ l7) << 3);
#pragma unroll
        for (int cd = 0; cd < 4; ++cd)
            avoff[c][cd] = (16 * cd + l15) * 64 + (((2 * c + (qg >> 1)) ^ l7) << 3) + (qg & 1) * 4;
    }

    f32x4 oacc[4] = {};   // O^T: D col=q=l15, row=d=16cd+qg*4+reg
    float lsum = 0.f;

    for (int kt = 0; kt < 16; ++kt) {
        const int cur = kt & 1;
        WAIT_VM0;
        BAR;
        CFENCE;
        if (kt < 15) stage(cur ^ 1, kt + 1);

        f32x4 sacc[4] = {};
#pragma unroll
        for (int c = 0; c < 4; ++c) {
#pragma unroll
            for (int kc = 0; kc < 2; ++kc) {
                bf16x8 ak = *(const bf16x8*)&Ks[cur][akoff[c][kc]];
                sacc[c] = __builtin_amdgcn_mfma_f32_16x16x32_bf16(ak, bq[kc], sacc[c], 0, 0, 0);
            }
        }

        s16x4 pf[4];
#pragma unroll
        for (int c = 0; c < 4; ++c) {
            float p0 = __builtin_amdgcn_exp2f(sacc[c][0]);
            float p1 = __builtin_amdgcn_exp2f(sacc[c][1]);
            float p2 = __builtin_amdgcn_exp2f(sacc[c][2]);
            float p3 = __builtin_amdgcn_exp2f(sacc[c][3]);
            lsum += (p0 + p1) + (p2 + p3);
            union { uint2 u; s16x4 v; } pk;
            pk.u.x = pkbf(p0, p1); pk.u.y = pkbf(p2, p3);
            pf[c] = pk.v;
        }

#pragma unroll
        for (int c = 0; c < 4; ++c) {
            s16x4 av[4];
#pragma unroll
            for (int cd = 0; cd < 4; ++cd)
                av[cd] = *(const s16x4*)&Vs[cur][avoff[c][cd]];
#pragma unroll
            for (int cd = 0; cd < 4; ++cd)
                oacc[cd] = __builtin_amdgcn_mfma_f32_16x16x16bf16_1k(av[cd], pf[c], oacc[cd], 0, 0, 0);
        }
    }

    lsum += __shfl_xor(lsum, 16);
    lsum += __shfl_xor(lsum, 32);

    const int b = bh / NH, h = bh % NH;
    const float inv = 1.f / lsum;
    const int qrow = qt * 128 + 16 * wv + l15;
    u16* orow = attn_out + (size_t)(b * SEQ + qrow) * DIM + h * HD + qg * 4;
#pragma unroll
    for (int cd = 0; cd < 4; ++cd) {
        ushort4 o;
        o.x = f2bf(oacc[cd][0] * inv); o.y = f2bf(oacc[cd][1] * inv);
        o.z = f2bf(oacc[cd][2] * inv); o.w = f2bf(oacc[cd][3] * inv);
        *(ushort4*)&orow[16 * cd] = o;
    }
}

extern "C" void kernel_launch(void* const* d_in, const int* in_sizes, int n_in,
                              void* d_out, int out_size, void* d_ws, size_t ws_size,
                              hipStream_t stream) {
    const float* x      = (const float*)d_in[0];
    const float* w_qkv  = (const float*)d_in[1];
    const float* b_qkv  = (const float*)d_in[2];
    const float* w_proj = (const float*)d_in[3];
    const float* b_proj = (const float*)d_in[4];
    float* out = (float*)d_out;
    u16* ws = (u16*)d_ws;

    prep<<<3648, 256, 0, stream>>>(x, w_qkv, w_proj, ws);
    gemm_bt<1, 4><<<dim3(18, 64), 256, 0, stream>>>(ws + XOFF, ws + WQOFF, b_qkv, nullptr, ws);
    flash_attn<<<dim3(8, 96), 512, 0, stream>>>(ws, ws + AOFF);
    gemm_bt<0, 2><<<dim3(12, 64), 256, 0, stream>>>(ws + AOFF, ws + WPOFF, b_proj, out, nullptr);
}